// Round 8
// baseline (80.706 us; speedup 1.0000x reference)
//
#include <hip/hip_runtime.h>

// out[b,o,i,j] = bias[o] + sum_{c,r,s} w[o,c,r,s] * xpad[b,c,i+r,j+s]
// (reference's FFT circular-conv + roll + slice == conv2d pad=1; pruning
//  deviation + bf16 rounding = 0.033 absmax < 0.084 threshold)
//
// R8: single fused dispatch. Block = (batch, row, 64-col half), 4 waves.
// Stage x halo slab (3x66x32) NCHW fp32 -> LDS bf16 [row][col][ch] with
// zero-pad applied at stage time (no masks in MFMA loop); stage w -> LDS
// [tap][o][c] bf16; ONE barrier; R5-verified MFMA lane mappings, frags via
// ds_read_b128. Removes prep dispatch + graph gap + 8 MB xt round-trip.
// Timed window otherwise = harness poison fills (~48 us @ HBM roofline).

typedef __attribute__((ext_vector_type(8))) short short8;
typedef __attribute__((ext_vector_type(4))) float f32x4;
typedef __attribute__((ext_vector_type(4))) unsigned int u32x4;

__device__ __forceinline__ unsigned short f2bf(float f) {
    unsigned int u = __builtin_bit_cast(unsigned int, f);
    u += 0x7FFFu + ((u >> 16) & 1u);          // round-to-nearest-even
    return (unsigned short)(u >> 16);
}

__global__ __launch_bounds__(256, 4)
void conv_fused(const float* __restrict__ x, const float* __restrict__ w,
                const float* __restrict__ bias, float* __restrict__ out) {
    const int tid  = threadIdx.x;
    const int blk  = blockIdx.x;          // 4b x 128row x 2half
    const int b    = blk >> 8;
    const int i    = (blk >> 1) & 127;
    const int half = blk & 1;
    const int c0   = half * 64;           // first output col of this block

    __shared__ __align__(16) unsigned int   xls[3 * 66 * 16];   // [r][l][cpair]
    __shared__ __align__(16) unsigned short wls[9 * 32 * 32];   // [t][o][c]

    // ---- stage weights: dst-linear, 36 elts/thread ----
    #pragma unroll
    for (int k = 0; k < 36; ++k) {
        const int idx = tid + 256 * k;            // [0, 9216)
        const int t = idx >> 10;
        const int o = (idx >> 5) & 31;
        const int c = idx & 31;
        wls[idx] = f2bf(w[(o * 32 + c) * 9 + t]);
    }

    // ---- stage x halo slab: rows i-1..i+1, cols c0-1..c0+64, 32 ch ----
    const float* xb = x + ((size_t)b << 19);      // b*32*16384
    const int p  = tid & 15;                      // channel pair
    const int l0 = tid >> 4;                      // col-chunk base
    #pragma unroll
    for (int r = 0; r < 3; ++r) {
        const int gi  = i - 1 + r;
        const bool rok = (unsigned)gi < 128u;
        const int gic = min(max(gi, 0), 127);
        #pragma unroll
        for (int pass = 0; pass < 5; ++pass) {
            const int l = l0 + 16 * pass;
            if (l < 66) {
                const int gj  = c0 - 1 + l;
                const bool ok = rok && ((unsigned)gj < 128u);
                const int gjc = min(max(gj, 0), 127);
                const size_t base = (size_t)gic * 128 + gjc;
                float f0 = xb[((size_t)(2 * p)     << 14) + base];
                float f1 = xb[((size_t)(2 * p + 1) << 14) + base];
                if (!ok) { f0 = 0.f; f1 = 0.f; }
                xls[(r * 66 + l) * 16 + p] =
                    (unsigned)f2bf(f0) | ((unsigned)f2bf(f1) << 16);
            }
        }
    }
    __syncthreads();   // the only barrier

    // ---- MFMA: wave = 16-pixel group, all 32 o's ----
    const int wave = tid >> 6;
    const int lane = tid & 63;
    const int lm   = lane & 15;     // n: pixel / m: o within 16-tile
    const int quad = lane >> 4;
    const int q8   = quad * 8;      // channel sub-range base

    // A-frags: A[m=lm][k=q8+jj] = w[o=mt*16+lm][c=q8+jj][tap t]
    u32x4 af[9][2];
    #pragma unroll
    for (int t = 0; t < 9; ++t)
        #pragma unroll
        for (int mt = 0; mt < 2; ++mt)
            af[t][mt] = *(const u32x4*)(wls + ((t * 32 + mt * 16 + lm) * 32 + q8));

    f32x4 acc0 = {0.f, 0.f, 0.f, 0.f};
    f32x4 acc1 = {0.f, 0.f, 0.f, 0.f};

    #pragma unroll
    for (int t = 0; t < 9; ++t) {
        const int r = t / 3, s = t - 3 * r;
        const int l = wave * 16 + lm + s;         // halo col (pad pre-applied)
        const u32x4 bv = *(const u32x4*)(xls + ((r * 66 + l) * 16 + quad * 4));
        const short8 bs = __builtin_bit_cast(short8, bv);
        acc0 = __builtin_amdgcn_mfma_f32_16x16x32_bf16(
                   __builtin_bit_cast(short8, af[t][0]), bs, acc0, 0, 0, 0);
        acc1 = __builtin_amdgcn_mfma_f32_16x16x32_bf16(
                   __builtin_bit_cast(short8, af[t][1]), bs, acc1, 0, 0, 0);
    }

    // D: col = lm = pixel, row = quad*4+reg = o within 16-tile
    const int j0 = c0 + wave * 16;
    const size_t pixbase = (size_t)i * 128 + j0 + lm;
    #pragma unroll
    for (int reg = 0; reg < 4; ++reg) {
        const int o0 = quad * 4 + reg;            // m-tile 0
        const int o1 = 16 + o0;                   // m-tile 1
        out[((size_t)(b * 32 + o0) << 14) + pixbase] = acc0[reg] + bias[o0];
        out[((size_t)(b * 32 + o1) << 14) + pixbase] = acc1[reg] + bias[o1];
    }
}

extern "C" void kernel_launch(void* const* d_in, const int* in_sizes, int n_in,
                              void* d_out, int out_size, void* d_ws, size_t ws_size,
                              hipStream_t stream) {
    const float* x    = (const float*)d_in[0];
    const float* w    = (const float*)d_in[1];
    const float* bias = (const float*)d_in[2];
    float* out = (float*)d_out;
    hipLaunchKernelGGL(conv_fused, dim3(1024), dim3(256), 0, stream,
                       x, w, bias, out);
}

// Round 9
// 75.342 us; speedup vs baseline: 1.0712x; 1.0712x over previous
//
#include <hip/hip_runtime.h>

// out[b,o,i,j] = bias[o] + sum_{c,r,s} w[o,c,r,s] * xpad[b,c,i+r,j+s]
// (reference's FFT circular-conv + roll + slice == conv2d pad=1; pruning
//  deviation + bf16 rounding = 0.033 absmax < 0.084 threshold)
//
// R9: revert R8 fusion (per-block w re-staging + uncoalesced halo staging
// cost more than it saved). Back to R7 two-dispatch pipeline, but fix the
// conv's grid-limited latency binding (1024 blocks = 16 waves/CU, ~27 VMEM
// ops/wave): split the two o-tiles across waves -> 8192 waves / 2048 blocks,
// half the per-wave footprint, 2x the TLP. prep unchanged from R7.

typedef __attribute__((ext_vector_type(8))) short short8;
typedef __attribute__((ext_vector_type(4))) float f32x4;
typedef __attribute__((ext_vector_type(4))) unsigned int u32x4;

__device__ __forceinline__ unsigned short f2bf(float f) {
    unsigned int u = __builtin_bit_cast(unsigned int, f);
    u += 0x7FFFu + ((u >> 16) & 1u);          // round-to-nearest-even
    return (unsigned short)(u >> 16);
}

// blocks 0..1023 : x (4,32,128,128) fp32 NCHW -> xt (4,16384,32) bf16
// blocks 1024..1059: w (32,32,3,3) fp32 -> wt[(t*32+o)*32+c] bf16 (1 elt/thread)
__global__ __launch_bounds__(256)
void prep(const float* __restrict__ x, const float* __restrict__ w,
          unsigned short* __restrict__ xt, unsigned short* __restrict__ wt) {
    const int blk = blockIdx.x;
    const int tid = threadIdx.x;
    if (blk < 1024) {
        const int idx = blk * 256 + tid;      // [0, 262144)
        const int pg  = idx >> 2;             // b*16384 + px
        const int q   = idx & 3;              // channel octet
        const int b   = pg >> 14;
        const int px  = pg & 16383;
        const float* xp = x + ((size_t)(b * 32 + q * 8) << 14) + px;
        unsigned int u[4];
        #pragma unroll
        for (int cp = 0; cp < 4; ++cp) {
            const float f0 = xp[(size_t)(2 * cp) << 14];
            const float f1 = xp[(size_t)(2 * cp + 1) << 14];
            u[cp] = (unsigned)f2bf(f0) | ((unsigned)f2bf(f1) << 16);
        }
        u32x4 v; v[0] = u[0]; v[1] = u[1]; v[2] = u[2]; v[3] = u[3];
        *(u32x4*)(xt + (size_t)pg * 32 + q * 8) = v;
    } else {
        const int idx = (blk - 1024) * 256 + tid;   // [0, 9216)
        const int t = idx >> 10;
        const int o = (idx >> 5) & 31;
        const int c = idx & 31;
        wt[idx] = f2bf(w[(o * 32 + c) * 9 + t]);
    }
}

// wave = (16-pixel group, one 16-o m-tile): 9 A-frags, 9 B-loads, 9 MFMAs.
__global__ __launch_bounds__(256, 6)
void conv_mfma(const unsigned short* __restrict__ xt,
               const unsigned short* __restrict__ wt,
               const float* __restrict__ bias,
               float* __restrict__ out) {
    const int tid  = threadIdx.x;
    const int wave = tid >> 6;
    const int lane = tid & 63;
    const int lm   = lane & 15;     // n: pixel within group / m: o within tile
    const int quad = lane >> 4;
    const int q8   = quad * 8;      // k-subrange base (channel)

    const int gw = blockIdx.x * 4 + wave;   // [0, 8192)
    const int g  = gw >> 1;                 // pixel group id, [0, 4096)
    const int mt = gw & 1;                  // m-tile (o-half)
    const int b  = g >> 10;
    const int i  = (g >> 3) & 127;
    const int j0 = (g & 7) * 16;
    const int j  = j0 + lm;

    // A-frags: A[m=lm][k=q8+jj] = w[o=mt*16+lm][c=q8+jj][tap t]
    u32x4 af[9];
    #pragma unroll
    for (int t = 0; t < 9; ++t)
        af[t] = *(const u32x4*)(wt + ((t * 32 + mt * 16 + lm) * 32 + q8));

    f32x4 acc = {0.f, 0.f, 0.f, 0.f};
    const unsigned short* xb = xt + (size_t)b * 16384 * 32;

    #pragma unroll
    for (int t = 0; t < 9; ++t) {
        const int r  = t / 3, s = t - 3 * r;
        const int si = i + r - 1;               // group-uniform
        const int sj = j + s - 1;               // per-lane (edges only)
        const bool ok = ((unsigned)si < 128u) && ((unsigned)sj < 128u);
        const int ci = min(max(si, 0), 127);
        const int cj = min(max(sj, 0), 127);
        // B-frag: B[k=q8+jj][n=lm] = xt[b][src_pix][c=q8+jj] -- one 16B load
        u32x4 bv = *(const u32x4*)(xb + ((size_t)(ci * 128 + cj) * 32 + q8));
        const unsigned msk = ok ? 0xFFFFFFFFu : 0u;
        bv &= msk;                              // zero-pad outside image
        acc = __builtin_amdgcn_mfma_f32_16x16x32_bf16(
                  __builtin_bit_cast(short8, af[t]),
                  __builtin_bit_cast(short8, bv), acc, 0, 0, 0);
    }

    // D: col = lm = pixel, row = quad*4+reg = o within 16-tile
    const size_t pixbase = (size_t)i * 128 + j0 + lm;
    #pragma unroll
    for (int reg = 0; reg < 4; ++reg) {
        const int o = mt * 16 + quad * 4 + reg;
        out[((size_t)(b * 32 + o) << 14) + pixbase] = acc[reg] + bias[o];
    }
}

extern "C" void kernel_launch(void* const* d_in, const int* in_sizes, int n_in,
                              void* d_out, int out_size, void* d_ws, size_t ws_size,
                              hipStream_t stream) {
    const float* x    = (const float*)d_in[0];
    const float* w    = (const float*)d_in[1];
    const float* bias = (const float*)d_in[2];
    float* out = (float*)d_out;

    unsigned short* xt = (unsigned short*)d_ws;                       // 4 MiB
    unsigned short* wt = (unsigned short*)((char*)d_ws + (4 << 20));  // 18 KiB

    hipLaunchKernelGGL(prep,      dim3(1060), dim3(256), 0, stream, x, w, xt, wt);
    hipLaunchKernelGGL(conv_mfma, dim3(2048), dim3(256), 0, stream,
                       xt, wt, bias, out);
}

// Round 10
// 73.170 us; speedup vs baseline: 1.1030x; 1.0297x over previous
//
#include <hip/hip_runtime.h>

// out[b,o,i,j] = bias[o] + sum_{c,r,s} w[o,c,r,s] * xpad[b,c,i+r,j+s]
// (reference's FFT circular-conv + roll + slice == conv2d pad=1; pruning
//  deviation + bf16 rounding = 0.033 absmax < 0.084 threshold)
//
// R10: revert to R7 (measured best, 74.0 us). Window model fitted over all
// rounds: ~42 us harness d_ws poison fill (268 MB @ ~80% HBM peak) + ~26 us
// harness tiny-reset dispatches/graph gaps + prep ~3 us (16 MB traffic,
// ~2.5 us floor) + conv ~3 us (16.4 MB traffic, ~2.6 us floor; MFMA busy
// ~0.6 us). Addressable slack < 4% of window -> this is the ceiling.
// conv block k reads the xt range prep block k wrote (same-XCD L2 reuse).

typedef __attribute__((ext_vector_type(8))) short short8;
typedef __attribute__((ext_vector_type(4))) float f32x4;
typedef __attribute__((ext_vector_type(4))) unsigned int u32x4;

__device__ __forceinline__ unsigned short f2bf(float f) {
    unsigned int u = __builtin_bit_cast(unsigned int, f);
    u += 0x7FFFu + ((u >> 16) & 1u);          // round-to-nearest-even
    return (unsigned short)(u >> 16);
}

// blocks 0..1023 : x (4,32,128,128) fp32 NCHW -> xt (4,16384,32) bf16
// blocks 1024..1059: w (32,32,3,3) fp32 -> wt[(t*32+o)*32+c] bf16 (1 elt/thread)
__global__ __launch_bounds__(256)
void prep(const float* __restrict__ x, const float* __restrict__ w,
          unsigned short* __restrict__ xt, unsigned short* __restrict__ wt) {
    const int blk = blockIdx.x;
    const int tid = threadIdx.x;
    if (blk < 1024) {
        const int idx = blk * 256 + tid;      // [0, 262144)
        const int pg  = idx >> 2;             // b*16384 + px
        const int q   = idx & 3;              // channel octet
        const int b   = pg >> 14;
        const int px  = pg & 16383;
        const float* xp = x + ((size_t)(b * 32 + q * 8) << 14) + px;
        unsigned int u[4];
        #pragma unroll
        for (int cp = 0; cp < 4; ++cp) {
            const float f0 = xp[(size_t)(2 * cp) << 14];
            const float f1 = xp[(size_t)(2 * cp + 1) << 14];
            u[cp] = (unsigned)f2bf(f0) | ((unsigned)f2bf(f1) << 16);
        }
        u32x4 v; v[0] = u[0]; v[1] = u[1]; v[2] = u[2]; v[3] = u[3];
        *(u32x4*)(xt + (size_t)pg * 32 + q * 8) = v;
    } else {
        const int idx = (blk - 1024) * 256 + tid;   // [0, 9216)
        const int t = idx >> 10;
        const int o = (idx >> 5) & 31;
        const int c = idx & 31;
        wt[idx] = f2bf(w[(o * 32 + c) * 9 + t]);
    }
}

// wave = 16-pixel group x all 32 o's: 18 A-frags, 9 B-loads, 18 MFMAs.
__global__ __launch_bounds__(256, 4)
void conv_mfma(const unsigned short* __restrict__ xt,
               const unsigned short* __restrict__ wt,
               const float* __restrict__ bias,
               float* __restrict__ out) {
    const int tid  = threadIdx.x;
    const int wave = tid >> 6;
    const int lane = tid & 63;
    const int lm   = lane & 15;     // n: pixel within group / m: o within tile
    const int quad = lane >> 4;
    const int q8   = quad * 8;      // k-subrange base (channel)

    const int g  = blockIdx.x * 4 + wave;   // pixel group id, [0, 4096)
    const int b  = g >> 10;
    const int i  = (g >> 3) & 127;
    const int j0 = (g & 7) * 16;
    const int j  = j0 + lm;

    // A-frags: A[m=lane&15][k=quad*8+jj] ; value = w[o=mt*16+lm][c=q8+jj][tap t]
    u32x4 af[9][2];
    #pragma unroll
    for (int t = 0; t < 9; ++t)
        #pragma unroll
        for (int mt = 0; mt < 2; ++mt)
            af[t][mt] = *(const u32x4*)(wt + ((t * 32 + mt * 16 + lm) * 32 + q8));

    f32x4 acc0 = {0.f, 0.f, 0.f, 0.f};
    f32x4 acc1 = {0.f, 0.f, 0.f, 0.f};
    const unsigned short* xb = xt + (size_t)b * 16384 * 32;

    #pragma unroll
    for (int t = 0; t < 9; ++t) {
        const int r  = t / 3, s = t - 3 * r;
        const int si = i + r - 1;               // group-uniform
        const int sj = j + s - 1;               // per-lane (edges only)
        const bool ok = ((unsigned)si < 128u) && ((unsigned)sj < 128u);
        const int ci = min(max(si, 0), 127);
        const int cj = min(max(sj, 0), 127);
        // B-frag: B[k=q8+jj][n=lm] = xt[b][src_pix][c=q8+jj] -- one 16B load
        u32x4 bv = *(const u32x4*)(xb + ((size_t)(ci * 128 + cj) * 32 + q8));
        const unsigned msk = ok ? 0xFFFFFFFFu : 0u;
        bv &= msk;                              // zero-pad outside image
        const short8 bs = __builtin_bit_cast(short8, bv);
        acc0 = __builtin_amdgcn_mfma_f32_16x16x32_bf16(
                   __builtin_bit_cast(short8, af[t][0]), bs, acc0, 0, 0, 0);
        acc1 = __builtin_amdgcn_mfma_f32_16x16x32_bf16(
                   __builtin_bit_cast(short8, af[t][1]), bs, acc1, 0, 0, 0);
    }

    // D: col = lane&15 = pixel, row = quad*4+reg = o within 16-tile
    const size_t pixbase = (size_t)i * 128 + j0 + lm;
    #pragma unroll
    for (int reg = 0; reg < 4; ++reg) {
        const int o0 = quad * 4 + reg;          // m-tile 0
        const int o1 = 16 + o0;                 // m-tile 1
        out[((size_t)(b * 32 + o0) << 14) + pixbase] = acc0[reg] + bias[o0];
        out[((size_t)(b * 32 + o1) << 14) + pixbase] = acc1[reg] + bias[o1];
    }
}

extern "C" void kernel_launch(void* const* d_in, const int* in_sizes, int n_in,
                              void* d_out, int out_size, void* d_ws, size_t ws_size,
                              hipStream_t stream) {
    const float* x    = (const float*)d_in[0];
    const float* w    = (const float*)d_in[1];
    const float* bias = (const float*)d_in[2];
    float* out = (float*)d_out;

    unsigned short* xt = (unsigned short*)d_ws;                       // 4 MiB
    unsigned short* wt = (unsigned short*)((char*)d_ws + (4 << 20));  // 18 KiB

    hipLaunchKernelGGL(prep,      dim3(1060), dim3(256), 0, stream, x, w, xt, wt);
    hipLaunchKernelGGL(conv_mfma, dim3(1024), dim3(256), 0, stream,
                       xt, wt, bias, out);
}